// Round 12
// baseline (449.733 us; speedup 1.0000x reference)
//
#include <hip/hip_runtime.h>

#define N_NODES 100000
#define E_EDGES 1600000
#define CIN 64
#define CHID 128
#define COUT 64
#define NT 64                         // nodes per GEMM block
#define NB ((N_NODES + NT - 1) / NT)  // 1563
#define RBLK 64                       // slab blocks for stat reduce
#define CAP 128                       // bucket capacity per node
#define SBLK 256                      // smom blocks
#define SROWS ((N_NODES + SBLK - 1) / SBLK)  // 391
#define SPSTRIDE 4160                 // 4096 S + 64 mean per smom partial

// ---------------- bucket scatter: counting-sort-free CSR --------------------
__global__ void bucket_kernel(const int* __restrict__ ei, int* __restrict__ cnt,
                              int2* __restrict__ es) {
    int e = blockIdx.x * blockDim.x + threadIdx.x;
    if (e < E_EDGES) {
        int src = ei[e];
        int dst = ei[E_EDGES + e];
        int p = atomicAdd(&cnt[dst], 1);
        if (p < CAP) es[((long)dst << 7) + p] = make_int2(e, src);
    }
}

// ---------------- gather: softmax-aggregate per node, fuse root add --------
// R11 proven form: 16-deep main loop, nontemporal ea.
__global__ void gather_kernel(const float* __restrict__ x,
                              const float* __restrict__ ea,
                              const int2* __restrict__ es,
                              const int* __restrict__ cnt,
                              float* __restrict__ h0) {
    int node = (blockIdx.x * blockDim.x + threadIdx.x) >> 6;
    int lane = threadIdx.x & 63;
    if (node >= N_NODES) return;
    long s = (long)node << 7;
    int n = cnt[node];
    n = n > CAP ? CAP : n;
    float nm = 0.f, dn = 0.f;
    int p = 0;
    for (; p + 16 <= n; p += 16) {
        int2 q[16];
#pragma unroll
        for (int u = 0; u < 16; ++u) q[u] = es[s + p + u];
        float av[16], xv[16];
#pragma unroll
        for (int u = 0; u < 16; ++u)
            av[u] = __builtin_nontemporal_load(ea + (long)q[u].x * CIN + lane);
#pragma unroll
        for (int u = 0; u < 16; ++u) xv[u] = x[(long)q[u].y * CIN + lane];
#pragma unroll
        for (int u = 0; u < 16; ++u) {
            float m = fmaxf(xv[u] + av[u], 0.f) + 1e-7f;
            float ex = __expf(m);
            nm = fmaf(m, ex, nm);
            dn += ex;
        }
    }
    for (; p + 8 <= n; p += 8) {
        int2 q[8];
#pragma unroll
        for (int u = 0; u < 8; ++u) q[u] = es[s + p + u];
        float av[8], xv[8];
#pragma unroll
        for (int u = 0; u < 8; ++u)
            av[u] = __builtin_nontemporal_load(ea + (long)q[u].x * CIN + lane);
#pragma unroll
        for (int u = 0; u < 8; ++u) xv[u] = x[(long)q[u].y * CIN + lane];
#pragma unroll
        for (int u = 0; u < 8; ++u) {
            float m = fmaxf(xv[u] + av[u], 0.f) + 1e-7f;
            float ex = __expf(m);
            nm = fmaf(m, ex, nm);
            dn += ex;
        }
    }
    for (; p + 4 <= n; p += 4) {
        int2 q[4];
#pragma unroll
        for (int u = 0; u < 4; ++u) q[u] = es[s + p + u];
        float av[4], xv[4];
#pragma unroll
        for (int u = 0; u < 4; ++u)
            av[u] = __builtin_nontemporal_load(ea + (long)q[u].x * CIN + lane);
#pragma unroll
        for (int u = 0; u < 4; ++u) xv[u] = x[(long)q[u].y * CIN + lane];
#pragma unroll
        for (int u = 0; u < 4; ++u) {
            float m = fmaxf(xv[u] + av[u], 0.f) + 1e-7f;
            float ex = __expf(m);
            nm = fmaf(m, ex, nm);
            dn += ex;
        }
    }
    for (; p < n; ++p) {
        int2 q = es[s + p];
        float m = fmaxf(x[(long)q.y * CIN + lane] + ea[(long)q.x * CIN + lane], 0.f) + 1e-7f;
        float ex = __expf(m);
        nm = fmaf(m, ex, nm);
        dn += ex;
    }
    h0[(long)node * CIN + lane] = nm / (dn + 1e-16f) + x[(long)node * CIN + lane];
}

// ---------------- smom: S = h0^T h0 partials + channel-sum partials ---------
// 256 blocks; thread owns 4x4 S-tile (i4 = (tid&15)*4, j4 = (tid>>4)*4).
__global__ void __launch_bounds__(256) smom_kernel(const float* __restrict__ h0,
                                                   float* __restrict__ Sp) {
    __shared__ float sh[64 * 64];  // 16 KiB tile
    int tid = threadIdx.x;
    int i4 = (tid & 15) * 4;
    int j4 = (tid >> 4) * 4;
    float acc[4][4];
#pragma unroll
    for (int a = 0; a < 4; ++a) { acc[a][0]=0.f; acc[a][1]=0.f; acc[a][2]=0.f; acc[a][3]=0.f; }
    float msum = 0.f;
    int n0 = blockIdx.x * SROWS;
    int n1 = n0 + SROWS;
    if (n1 > N_NODES) n1 = N_NODES;
    for (int t0 = n0; t0 < n1; t0 += 64) {
        int tn = n1 - t0; if (tn > 64) tn = 64;
        __syncthreads();
        for (int idx = tid * 4; idx < 64 * 64; idx += 1024) {
            int nl = idx >> 6;
            float4 v = make_float4(0.f, 0.f, 0.f, 0.f);
            if (nl < tn) v = *(const float4*)&h0[(long)(t0 + nl) * CIN + (idx & 63)];
            *(float4*)&sh[idx] = v;
        }
        __syncthreads();
#pragma unroll 2
        for (int nl = 0; nl < tn; ++nl) {
            float hi[4], hj[4];
#pragma unroll
            for (int a = 0; a < 4; ++a) hi[a] = sh[nl * 64 + i4 + a];
#pragma unroll
            for (int b = 0; b < 4; ++b) hj[b] = sh[nl * 64 + j4 + b];
#pragma unroll
            for (int a = 0; a < 4; ++a)
#pragma unroll
                for (int b = 0; b < 4; ++b) acc[a][b] = fmaf(hi[a], hj[b], acc[a][b]);
            if (tid < 64) msum += sh[nl * 64 + tid];
        }
    }
    float* p = Sp + (long)blockIdx.x * SPSTRIDE;
#pragma unroll
    for (int a = 0; a < 4; ++a)
        *(float4*)&p[(i4 + a) * 64 + j4] = make_float4(acc[a][0], acc[a][1], acc[a][2], acc[a][3]);
    if (tid < 64) p[4096 + tid] = msum;
}

// ---------------- sred: reduce S partials; last block -> BN1 mean/rstd ------
// mr1 layout: [mean_lin(128) | rstd(128)]  (b1 cancels inside BN)
__global__ void __launch_bounds__(256) sred_kernel(const float* __restrict__ Sp,
        const float* __restrict__ W1, float* __restrict__ Sfull,
        float* __restrict__ mr1, float invN, int* __restrict__ ticket) {
    int tid = threadIdx.x;
    int idx = blockIdx.x * 256 + tid;   // 0..4095
    float s = 0.f;
    for (int p = 0; p < SBLK; ++p) s += Sp[(long)p * SPSTRIDE + idx];
    Sfull[idx] = s;
    if (blockIdx.x == 0 && tid < 64) {
        float m = 0.f;
        for (int p = 0; p < SBLK; ++p) m += Sp[(long)p * SPSTRIDE + 4096 + tid];
        Sfull[4096 + tid] = m;
    }
    __threadfence();
    __shared__ int lastFlag;
    if (tid == 0) lastFlag = (atomicAdd(ticket, 1) == (int)gridDim.x - 1);
    __syncthreads();
    if (!lastFlag) return;
    __threadfence();
    __shared__ float sS[4096 + 64];   // 16.25 KiB
    __shared__ float sW[CIN * CHID];  // 32 KiB
    __shared__ float redQ[256], redM[256];
    for (int k = tid; k < 4096 + 64; k += 256) sS[k] = Sfull[k];
    for (int k = tid; k < CIN * CHID; k += 256) sW[k] = W1[k];
    __syncthreads();
    int j = tid & 127;
    int half = tid >> 7;               // i in [half*32, half*32+32)
    float q = 0.f, ml = 0.f;
    for (int i = half * 32; i < half * 32 + 32; ++i) {
        float wi = sW[i * CHID + j];
        float inner = 0.f;
#pragma unroll 4
        for (int k = 0; k < 64; ++k) inner = fmaf(sS[i * 64 + k], sW[k * CHID + j], inner);
        q = fmaf(wi, inner, q);
        ml = fmaf(sS[4096 + i], wi, ml);
    }
    redQ[tid] = q; redM[tid] = ml;
    __syncthreads();
    if (tid < 128) {
        float qf = redQ[tid] + redQ[tid + 128];
        float mlf = (redM[tid] + redM[tid + 128]) * invN;
        float var = qf * invN - mlf * mlf;
        mr1[tid] = mlf;
        mr1[128 + tid] = rsqrtf(fmaxf(var, 0.f) + 1e-5f);
    }
}

// ---------------- gemm12: fused (h0@W1) -> BN1+relu -> @W2+b2 -> h2 + P2 ----
__global__ void __launch_bounds__(256) gemm12_kernel(
        const float* __restrict__ h0, const float* __restrict__ W1,
        const float* __restrict__ mr1, const float* __restrict__ g1v,
        const float* __restrict__ be1v,
        const float* __restrict__ W2, const float* __restrict__ b2,
        float* __restrict__ h2, float* __restrict__ P) {
    __shared__ float lds[20480];       // 80 KiB: W1/sr | W2 | sh(->red)
    float* sW1 = lds;                  // [0, 8192)
    float* sW2 = lds + 8192;           // [8192, 16384)
    float* sh  = lds + 16384;          // [16384, 20480)
    int tid = threadIdx.x;
    int nbase = blockIdx.x * NT;
    for (int i = tid * 4; i < 8192; i += 1024) *(float4*)&sW1[i] = *(const float4*)&W1[i];
    for (int i = tid * 4; i < 8192; i += 1024) *(float4*)&sW2[i] = *(const float4*)&W2[i];
    for (int i = tid * 4; i < 4096; i += 1024) {
        int node = nbase + (i >> 6);
        float4 v = make_float4(0.f, 0.f, 0.f, 0.f);
        if (node < N_NODES) v = *(const float4*)&h0[(long)node * CIN + (i & 63)];
        *(float4*)&sh[i] = v;
    }
    __syncthreads();
    // ---- phase A: lin = h0 @ W1 (no bias; it cancels in BN) ----
    int js = (tid & 31) * 4;  // of 128
    int r  = tid >> 5;        // 8 nodes
    float acc[8][4];
#pragma unroll
    for (int i = 0; i < 8; ++i) { acc[i][0]=0.f; acc[i][1]=0.f; acc[i][2]=0.f; acc[i][3]=0.f; }
#pragma unroll 4
    for (int k = 0; k < CIN; ++k) {
        float4 w = *(float4*)&sW1[k * CHID + js];
#pragma unroll
        for (int i = 0; i < 8; ++i) {
            float a = sh[(r * 8 + i) * CIN + k];
            acc[i][0] = fmaf(a, w.x, acc[i][0]);
            acc[i][1] = fmaf(a, w.y, acc[i][1]);
            acc[i][2] = fmaf(a, w.z, acc[i][2]);
            acc[i][3] = fmaf(a, w.w, acc[i][3]);
        }
    }
    float4 mn = *(const float4*)&mr1[js];
    float4 rs = *(const float4*)&mr1[128 + js];
    float4 gg = *(const float4*)&g1v[js];
    float4 bb = *(const float4*)&be1v[js];
    __syncthreads();                   // all sW1/sh reads done
    float* sr = lds;                   // overwrite W1 region: [64 nodes][128]
#pragma unroll
    for (int i = 0; i < 8; ++i) {
        float4 v;
        v.x = fmaxf((acc[i][0] - mn.x) * rs.x * gg.x + bb.x, 0.f);
        v.y = fmaxf((acc[i][1] - mn.y) * rs.y * gg.y + bb.y, 0.f);
        v.z = fmaxf((acc[i][2] - mn.z) * rs.z * gg.z + bb.z, 0.f);
        v.w = fmaxf((acc[i][3] - mn.w) * rs.w * gg.w + bb.w, 0.f);
        *(float4*)&sr[(r * 8 + i) * CHID + js] = v;
    }
    __syncthreads();
    // ---- phase B: h2 = relu'd @ W2 + b2, BN2 partials ----
    int js2 = (tid & 15) * 4; // of 64
    int r2  = tid >> 4;       // 4 nodes
    float4 b2v = *(const float4*)&b2[js2];
    float acc2[4][4];
#pragma unroll
    for (int i = 0; i < 4; ++i) { acc2[i][0]=b2v.x; acc2[i][1]=b2v.y; acc2[i][2]=b2v.z; acc2[i][3]=b2v.w; }
#pragma unroll 4
    for (int k = 0; k < CHID; ++k) {
        float4 w = *(float4*)&sW2[k * COUT + js2];
#pragma unroll
        for (int i = 0; i < 4; ++i) {
            float a = sr[(r2 * 4 + i) * CHID + k];
            acc2[i][0] = fmaf(a, w.x, acc2[i][0]);
            acc2[i][1] = fmaf(a, w.y, acc2[i][1]);
            acc2[i][2] = fmaf(a, w.z, acc2[i][2]);
            acc2[i][3] = fmaf(a, w.w, acc2[i][3]);
        }
    }
    float s1[4] = {0,0,0,0}, s2[4] = {0,0,0,0};
#pragma unroll
    for (int i = 0; i < 4; ++i) {
        int node = nbase + r2 * 4 + i;
        if (node < N_NODES) {
            *(float4*)&h2[(long)node * COUT + js2] =
                make_float4(acc2[i][0], acc2[i][1], acc2[i][2], acc2[i][3]);
#pragma unroll
            for (int jj = 0; jj < 4; ++jj) {
                s1[jj] += acc2[i][jj];
                s2[jj] += acc2[i][jj] * acc2[i][jj];
            }
        }
    }
    __syncthreads();
    float* red = lds + 16384;          // [16][64] s1 | [16][64] s2
    *(float4*)&red[r2 * 64 + js2]        = make_float4(s1[0], s1[1], s1[2], s1[3]);
    *(float4*)&red[1024 + r2 * 64 + js2] = make_float4(s2[0], s2[1], s2[2], s2[3]);
    __syncthreads();
    if (tid < 128) {
        int base = (tid < 64) ? tid : (1024 + tid - 64);
        float v = 0.f;
#pragma unroll
        for (int rr = 0; rr < 16; ++rr) v += red[base + rr * 64];
        P[(long)blockIdx.x * 128 + tid] = v;
    }
}

// ---------------- slab reduce with last-block-fused finalize ----------------
__global__ void reduce_slab_kernel(const float* __restrict__ P, int totrows,
                                   int rows_per, float* __restrict__ Q,
                                   float* __restrict__ mr, int C, float invN,
                                   int* __restrict__ ticket) {
    int C2 = blockDim.x;
    int t = threadIdx.x;
    long r0 = (long)blockIdx.x * rows_per;
    long r1 = r0 + rows_per;
    if (r1 > totrows) r1 = totrows;
    {
        float s0 = 0.f, s1 = 0.f, s2 = 0.f, s3 = 0.f;
        long r = r0;
        for (; r + 4 <= r1; r += 4) {
            s0 += P[(r + 0) * C2 + t];
            s1 += P[(r + 1) * C2 + t];
            s2 += P[(r + 2) * C2 + t];
            s3 += P[(r + 3) * C2 + t];
        }
        for (; r < r1; ++r) s0 += P[r * C2 + t];
        Q[(long)blockIdx.x * C2 + t] = (s0 + s1) + (s2 + s3);
    }
    __threadfence();
    __shared__ int lastFlag;
    if (t == 0) lastFlag = (atomicAdd(ticket, 1) == (int)gridDim.x - 1);
    __syncthreads();
    if (!lastFlag) return;
    __threadfence();
    float s0 = 0.f, s1 = 0.f, s2 = 0.f, s3 = 0.f;
    for (int r = 0; r < RBLK; r += 4) {
        s0 += Q[(long)(r + 0) * C2 + t];
        s1 += Q[(long)(r + 1) * C2 + t];
        s2 += Q[(long)(r + 2) * C2 + t];
        s3 += Q[(long)(r + 3) * C2 + t];
    }
    __shared__ float sm[256];
    sm[t] = (s0 + s1) + (s2 + s3);
    __syncthreads();
    if (t < C) {
        float m = sm[t] * invN;
        float v = sm[C + t] * invN - m * m;
        mr[t] = m;
        mr[C + t] = rsqrtf(fmaxf(v, 0.f) + 1e-5f);
    }
}

// ---------------- GEMM3: t3 = silu(BN2(h2)) @ Wl, in-block BN3 row ----------
__global__ void __launch_bounds__(256) gemm3_kernel(
        const float* __restrict__ h2, const float* __restrict__ mr2,
        const float* __restrict__ g, const float* __restrict__ be,
        const float* __restrict__ Wl,
        float* __restrict__ t3, float* __restrict__ P) {
    __shared__ float sW[COUT * COUT]; // 16 KiB (reused as stat scratch)
    __shared__ float sr[NT * COUT];   // 16 KiB
    int tid = threadIdx.x;
    int nbase = blockIdx.x * NT;
    for (int i = tid * 4; i < COUT * COUT; i += 1024)
        *(float4*)&sW[i] = *(const float4*)&Wl[i];
    for (int i = tid * 4; i < NT * COUT; i += 1024) {
        int node = nbase + (i >> 6);
        int j = i & 63;
        float4 v = make_float4(0.f, 0.f, 0.f, 0.f);
        if (node < N_NODES) {
            v = *(const float4*)&h2[(long)node * COUT + j];
            float4 mn = *(const float4*)&mr2[j];
            float4 rq = *(const float4*)&mr2[COUT + j];
            float4 gg = *(const float4*)&g[j];
            float4 bb = *(const float4*)&be[j];
            v.x = (v.x - mn.x) * rq.x * gg.x + bb.x;
            v.y = (v.y - mn.y) * rq.y * gg.y + bb.y;
            v.z = (v.z - mn.z) * rq.z * gg.z + bb.z;
            v.w = (v.w - mn.w) * rq.w * gg.w + bb.w;
            v.x = v.x / (1.f + __expf(-v.x));
            v.y = v.y / (1.f + __expf(-v.y));
            v.z = v.z / (1.f + __expf(-v.z));
            v.w = v.w / (1.f + __expf(-v.w));
        }
        *(float4*)&sr[i] = v;
    }
    __syncthreads();
    int js = (tid & 15) * 4;
    int r  = tid >> 4;
    float acc[4][4];
#pragma unroll
    for (int i = 0; i < 4; ++i) { acc[i][0]=0.f; acc[i][1]=0.f; acc[i][2]=0.f; acc[i][3]=0.f; }
#pragma unroll 4
    for (int k = 0; k < COUT; ++k) {
        float4 w = *(float4*)&sW[k * COUT + js];
#pragma unroll
        for (int i = 0; i < 4; ++i) {
            float a = sr[(r * 4 + i) * COUT + k];
            acc[i][0] = fmaf(a, w.x, acc[i][0]);
            acc[i][1] = fmaf(a, w.y, acc[i][1]);
            acc[i][2] = fmaf(a, w.z, acc[i][2]);
            acc[i][3] = fmaf(a, w.w, acc[i][3]);
        }
    }
    float s1[4] = {0,0,0,0}, s2[4] = {0,0,0,0};
#pragma unroll
    for (int i = 0; i < 4; ++i) {
        int node = nbase + r * 4 + i;
        if (node < N_NODES) {
            *(float4*)&t3[(long)node * COUT + js] =
                make_float4(acc[i][0], acc[i][1], acc[i][2], acc[i][3]);
#pragma unroll
            for (int jj = 0; jj < 4; ++jj) {
                s1[jj] += acc[i][jj];
                s2[jj] += acc[i][jj] * acc[i][jj];
            }
        }
    }
    __syncthreads();
    float* red = sW;
    *(float4*)&red[r * 64 + js]        = make_float4(s1[0], s1[1], s1[2], s1[3]);
    *(float4*)&red[1024 + r * 64 + js] = make_float4(s2[0], s2[1], s2[2], s2[3]);
    __syncthreads();
    if (tid < 128) {
        int base = (tid < 64) ? tid : (1024 + tid - 64);
        float v = 0.f;
#pragma unroll
        for (int rr = 0; rr < 16; ++rr) v += red[base + rr * 64];
        P[(long)blockIdx.x * 128 + tid] = v;
    }
}

// ---------------- final: out = silu(BN3(t3)), float4 ------------------------
__global__ void final_kernel(const float* __restrict__ t3, const float* __restrict__ mr3,
                             const float* __restrict__ g, const float* __restrict__ be,
                             float* __restrict__ out) {
    long i = ((long)blockIdx.x * blockDim.x + threadIdx.x) * 4;
    int j = (int)(i & 63);
    float4 v = *(const float4*)&t3[i];
    float4 mn = *(const float4*)&mr3[j];
    float4 rq = *(const float4*)&mr3[COUT + j];
    float4 gg = *(const float4*)&g[j];
    float4 bb = *(const float4*)&be[j];
    v.x = (v.x - mn.x) * rq.x * gg.x + bb.x;
    v.y = (v.y - mn.y) * rq.y * gg.y + bb.y;
    v.z = (v.z - mn.z) * rq.z * gg.z + bb.z;
    v.w = (v.w - mn.w) * rq.w * gg.w + bb.w;
    v.x = v.x / (1.f + __expf(-v.x));
    v.y = v.y / (1.f + __expf(-v.y));
    v.z = v.z / (1.f + __expf(-v.z));
    v.w = v.w / (1.f + __expf(-v.w));
    *(float4*)&out[i] = v;
}

extern "C" void kernel_launch(void* const* d_in, const int* in_sizes, int n_in,
                              void* d_out, int out_size, void* d_ws, size_t ws_size,
                              hipStream_t stream) {
    const float* x   = (const float*)d_in[0];
    const int*   ei  = (const int*)d_in[1];
    const float* ea  = (const float*)d_in[2];
    const float* W1  = (const float*)d_in[4];
    // d_in[5] = b1 (cancels inside BN1; unused)
    const float* gm  = (const float*)d_in[6];
    const float* bm  = (const float*)d_in[7];
    const float* W2  = (const float*)d_in[8];
    const float* b2  = (const float*)d_in[9];
    const float* g1  = (const float*)d_in[10];
    const float* be1 = (const float*)d_in[11];
    const float* Wl  = (const float*)d_in[12];
    const float* g2  = (const float*)d_in[13];
    const float* be2 = (const float*)d_in[14];
    float* out = (float*)d_out;

    // workspace (floats):
    //   h0[N*64] | scr[N*128] | h2[N*64] | Sfin[512] | Q[16384] | cnt[N] |
    //   tickets[4] | pad | es[N*CAP int2]
    // scr hosts: Sp (256*4160), Sfull (4160), P2, P3 (disjoint offsets)
    float* h0   = (float*)d_ws;
    float* scr  = h0 + (long)N_NODES * CIN;
    float* h2   = scr + (long)N_NODES * CHID;
    float* t3   = h0;   // h0 dead after gemm12
    float* Sfin = h2 + (long)N_NODES * COUT;
    float* Q    = Sfin + 512;
    int*   cnt  = (int*)(Q + RBLK * 256);
    int*   tickets = cnt + N_NODES;
    long   es_off = ((long)(N_NODES * CIN) + (long)N_NODES * CHID + (long)N_NODES * COUT
                     + 512 + RBLK * 256 + N_NODES + 4 + 255) & ~255L;
    int2*  es   = (int2*)((float*)d_ws + es_off);
    float* Sp    = scr;                 // 256*4160 = 1,064,960
    float* Sfull = scr + 1100000;       // 4160
    float* P2    = scr + 1200000;       // NB*128 = 200,064
    float* P3    = scr + 1500000;       // NB*128

    const float invN = 1.f / N_NODES;

    hipMemsetAsync(cnt, 0, ((size_t)N_NODES + 4) * sizeof(int), stream);

    bucket_kernel<<<(E_EDGES + 255) / 256, 256, 0, stream>>>(ei, cnt, es);
    gather_kernel<<<(N_NODES * 64 + 255) / 256, 256, 0, stream>>>(x, ea, es, cnt, h0);

    smom_kernel<<<SBLK, 256, 0, stream>>>(h0, Sp);
    sred_kernel<<<16, 256, 0, stream>>>(Sp, W1, Sfull, Sfin, invN, tickets + 0);

    const int rpA = (NB + RBLK - 1) / RBLK;   // 25

    gemm12_kernel<<<NB, 256, 0, stream>>>(h0, W1, Sfin, gm, bm, W2, b2, h2, P2);
    reduce_slab_kernel<<<RBLK, 128, 0, stream>>>(P2, NB, rpA, Q, Sfin + 256, COUT, invN, tickets + 1);
    gemm3_kernel<<<NB, 256, 0, stream>>>(h2, Sfin + 256, g1, be1, Wl, t3, P3);
    reduce_slab_kernel<<<RBLK, 128, 0, stream>>>(P3, NB, rpA, Q, Sfin + 384, COUT, invN, tickets + 2);
    final_kernel<<<(N_NODES * COUT / 4) / 256, 256, 0, stream>>>(t3, Sfin + 384, g2, be2, out);
}

// Round 13
// 391.278 us; speedup vs baseline: 1.1494x; 1.1494x over previous
//
#include <hip/hip_runtime.h>

#define N_NODES 100000
#define E_EDGES 1600000
#define CIN 64
#define CHID 128
#define COUT 64
#define NT 64                         // nodes per GEMM block
#define NB ((N_NODES + NT - 1) / NT)  // 1563
#define RBLK 64                       // slab blocks for stat reduce
#define CAP 128                       // bucket capacity per node

typedef float f32x4 __attribute__((ext_vector_type(4)));

// ---------------- bucket scatter: counting-sort-free CSR, 4 edges/thread ----
__global__ void bucket_kernel(const int* __restrict__ ei, int* __restrict__ cnt,
                              int2* __restrict__ es) {
    int e4 = (blockIdx.x * blockDim.x + threadIdx.x) * 4;
    if (e4 >= E_EDGES) return;
    int4 s = *(const int4*)&ei[e4];
    int4 d = *(const int4*)&ei[E_EDGES + e4];
    int p0 = atomicAdd(&cnt[d.x], 1);
    if (p0 < CAP) es[((long)d.x << 7) + p0] = make_int2(e4 + 0, s.x);
    int p1 = atomicAdd(&cnt[d.y], 1);
    if (p1 < CAP) es[((long)d.y << 7) + p1] = make_int2(e4 + 1, s.y);
    int p2 = atomicAdd(&cnt[d.z], 1);
    if (p2 < CAP) es[((long)d.z << 7) + p2] = make_int2(e4 + 2, s.z);
    int p3 = atomicAdd(&cnt[d.w], 1);
    if (p3 < CAP) es[((long)d.w << 7) + p3] = make_int2(e4 + 3, s.w);
}

// ---------------- gather: softmax-aggregate per node, fuse root add --------
// aggr = sum(msg*exp(msg)) / (sum(exp(msg)) + 1e-16); exp(max) cancels vs ref.
// Wave = node. 16 lanes x float4 per edge-row, 4 edge slots, unroll 8:
// up to 32 ea-rows + 32 x-rows in flight; deg<=32 completes in ONE iteration.
// Masked/clamped slots (R8-proven); butterfly combine across slots.
__global__ void gather_kernel(const float* __restrict__ x,
                              const float* __restrict__ ea,
                              const int2* __restrict__ es,
                              const int* __restrict__ cnt,
                              float* __restrict__ h0) {
    int node = (blockIdx.x * blockDim.x + threadIdx.x) >> 6;
    int lane = threadIdx.x & 63;
    if (node >= N_NODES) return;
    int eg = lane >> 4;         // edge slot 0..3
    int ch = (lane & 15) * 4;   // channel offset
    long s = (long)node << 7;
    int n = cnt[node];
    n = n > CAP ? CAP : n;
    f32x4 xr = *(const f32x4*)&x[(long)node * CIN + ch];
    if (n == 0) {
        if (eg == 0) *(f32x4*)&h0[(long)node * CIN + ch] = xr;
        return;
    }
    f32x4 nm = (f32x4)(0.f);
    f32x4 dn = (f32x4)(0.f);
    for (int p = 0; p < n; p += 32) {
        int2 q[8]; bool act[8];
#pragma unroll
        for (int u = 0; u < 8; ++u) {
            int idx = p + u * 4 + eg;
            act[u] = idx < n;
            idx = act[u] ? idx : n - 1;     // always a valid, written entry
            q[u] = es[s + idx];
        }
        f32x4 av[8], xv[8];
#pragma unroll
        for (int u = 0; u < 8; ++u)
            av[u] = __builtin_nontemporal_load(
                        reinterpret_cast<const f32x4*>(ea + (long)q[u].x * CIN + ch));
#pragma unroll
        for (int u = 0; u < 8; ++u)
            xv[u] = *reinterpret_cast<const f32x4*>(x + (long)q[u].y * CIN + ch);
#pragma unroll
        for (int u = 0; u < 8; ++u) {
#pragma unroll
            for (int c = 0; c < 4; ++c) {
                float m = fmaxf(xv[u][c] + av[u][c], 0.f) + 1e-7f;
                float e = act[u] ? __expf(m) : 0.f;
                nm[c] = fmaf(m, e, nm[c]);
                dn[c] += e;
            }
        }
    }
    // combine across the 4 edge slots (lanes differing in bits 4,5)
#pragma unroll
    for (int mask = 16; mask <= 32; mask <<= 1) {
#pragma unroll
        for (int c = 0; c < 4; ++c) {
            nm[c] += __shfl_xor(nm[c], mask);
            dn[c] += __shfl_xor(dn[c], mask);
        }
    }
    if (eg == 0) {
        f32x4 o;
#pragma unroll
        for (int c = 0; c < 4; ++c) o[c] = nm[c] / (dn[c] + 1e-16f) + xr[c];
        *(f32x4*)&h0[(long)node * CIN + ch] = o;
    }
}

// ---------------- slab reduce with last-block-fused finalize ----------------
// P is ONE row per GEMM block (in-block pre-reduced).
__global__ void reduce_slab_kernel(const float* __restrict__ P, int totrows,
                                   int rows_per, float* __restrict__ Q,
                                   float* __restrict__ mr, int C, float invN,
                                   int* __restrict__ ticket) {
    int C2 = blockDim.x;
    int t = threadIdx.x;
    long r0 = (long)blockIdx.x * rows_per;
    long r1 = r0 + rows_per;
    if (r1 > totrows) r1 = totrows;
    {
        float s0 = 0.f, s1 = 0.f, s2 = 0.f, s3 = 0.f;
        long r = r0;
        for (; r + 4 <= r1; r += 4) {
            s0 += P[(r + 0) * C2 + t];
            s1 += P[(r + 1) * C2 + t];
            s2 += P[(r + 2) * C2 + t];
            s3 += P[(r + 3) * C2 + t];
        }
        for (; r < r1; ++r) s0 += P[r * C2 + t];
        Q[(long)blockIdx.x * C2 + t] = (s0 + s1) + (s2 + s3);
    }
    __threadfence();
    __shared__ int lastFlag;
    if (t == 0) lastFlag = (atomicAdd(ticket, 1) == (int)gridDim.x - 1);
    __syncthreads();
    if (!lastFlag) return;
    __threadfence();
    float s0 = 0.f, s1 = 0.f, s2 = 0.f, s3 = 0.f;
    for (int r = 0; r < RBLK; r += 4) {
        s0 += Q[(long)(r + 0) * C2 + t];
        s1 += Q[(long)(r + 1) * C2 + t];
        s2 += Q[(long)(r + 2) * C2 + t];
        s3 += Q[(long)(r + 3) * C2 + t];
    }
    __shared__ float sm[256];
    sm[t] = (s0 + s1) + (s2 + s3);
    __syncthreads();
    if (t < C) {
        float m = sm[t] * invN;
        float v = sm[C + t] * invN - m * m;
        mr[t] = m;
        mr[C + t] = rsqrtf(fmaxf(v, 0.f) + 1e-5f);
    }
}

// ---------------- GEMM1: t1 = h0 @ W1 + b1, in-block BN1 partial row --------
__global__ void __launch_bounds__(256) gemm1_kernel(
        const float* __restrict__ h0, const float* __restrict__ W1,
        const float* __restrict__ b1, float* __restrict__ t1,
        float* __restrict__ P) {
    __shared__ float sW[CIN * CHID];  // 32 KiB (reused as stat scratch)
    __shared__ float sh[NT * CIN];    // 16 KiB
    int tid = threadIdx.x;
    int nbase = blockIdx.x * NT;
    for (int i = tid * 4; i < CIN * CHID; i += 1024)
        *(float4*)&sW[i] = *(const float4*)&W1[i];
    for (int i = tid * 4; i < NT * CIN; i += 1024) {
        int node = nbase + (i >> 6);
        float4 v = make_float4(0.f, 0.f, 0.f, 0.f);
        if (node < N_NODES) v = *(const float4*)&h0[(long)node * CIN + (i & 63)];
        *(float4*)&sh[i] = v;
    }
    __syncthreads();
    int js = (tid & 31) * 4;  // out channels js..js+3
    int r  = tid >> 5;        // node group, nodes r*8 .. r*8+7
    float4 bb = *(const float4*)&b1[js];
    float acc[8][4];
#pragma unroll
    for (int i = 0; i < 8; ++i) { acc[i][0]=bb.x; acc[i][1]=bb.y; acc[i][2]=bb.z; acc[i][3]=bb.w; }
#pragma unroll 4
    for (int k = 0; k < CIN; ++k) {
        float4 w = *(float4*)&sW[k * CHID + js];
#pragma unroll
        for (int i = 0; i < 8; ++i) {
            float a = sh[(r * 8 + i) * CIN + k];
            acc[i][0] = fmaf(a, w.x, acc[i][0]);
            acc[i][1] = fmaf(a, w.y, acc[i][1]);
            acc[i][2] = fmaf(a, w.z, acc[i][2]);
            acc[i][3] = fmaf(a, w.w, acc[i][3]);
        }
    }
    float s1[4] = {0,0,0,0}, s2[4] = {0,0,0,0};
#pragma unroll
    for (int i = 0; i < 8; ++i) {
        int node = nbase + r * 8 + i;
        if (node < N_NODES) {
            *(float4*)&t1[(long)node * CHID + js] =
                make_float4(acc[i][0], acc[i][1], acc[i][2], acc[i][3]);
#pragma unroll
            for (int jj = 0; jj < 4; ++jj) {
                s1[jj] += acc[i][jj];
                s2[jj] += acc[i][jj] * acc[i][jj];
            }
        }
    }
    // in-block stat reduction: 8 r-groups -> one row of 256 (128 s1 | 128 s2)
    __syncthreads();                 // all sW reads done; safe to reuse
    float* red = sW;                 // [8][128] s1, then [8][128] s2
    *(float4*)&red[r * 128 + js]        = make_float4(s1[0], s1[1], s1[2], s1[3]);
    *(float4*)&red[1024 + r * 128 + js] = make_float4(s2[0], s2[1], s2[2], s2[3]);
    __syncthreads();
    {
        int base = (tid < 128) ? tid : (1024 + tid - 128);
        float v = 0.f;
#pragma unroll
        for (int rr = 0; rr < 8; ++rr) v += red[base + rr * 128];
        P[(long)blockIdx.x * 256 + tid] = v;
    }
}

// ---------------- GEMM2: h2 = relu(BN1(t1)) @ W2 + b2, in-block BN2 row -----
__global__ void __launch_bounds__(256) gemm2_kernel(
        const float* __restrict__ t1, const float* __restrict__ mr1,
        const float* __restrict__ g, const float* __restrict__ be,
        const float* __restrict__ W2, const float* __restrict__ b2,
        float* __restrict__ h2, float* __restrict__ P) {
    __shared__ float sW[CHID * COUT]; // 32 KiB (reused as stat scratch)
    __shared__ float sr[NT * CHID];   // 32 KiB
    int tid = threadIdx.x;
    int nbase = blockIdx.x * NT;
    for (int i = tid * 4; i < CHID * COUT; i += 1024)
        *(float4*)&sW[i] = *(const float4*)&W2[i];
    for (int i = tid * 4; i < NT * CHID; i += 1024) {
        int node = nbase + (i >> 7);
        int j = i & 127;
        float4 v = make_float4(0.f, 0.f, 0.f, 0.f);
        if (node < N_NODES) {
            v = *(const float4*)&t1[(long)node * CHID + j];
            float4 mn = *(const float4*)&mr1[j];
            float4 rq = *(const float4*)&mr1[CHID + j];
            float4 gg = *(const float4*)&g[j];
            float4 bb = *(const float4*)&be[j];
            v.x = fmaxf((v.x - mn.x) * rq.x * gg.x + bb.x, 0.f);
            v.y = fmaxf((v.y - mn.y) * rq.y * gg.y + bb.y, 0.f);
            v.z = fmaxf((v.z - mn.z) * rq.z * gg.z + bb.z, 0.f);
            v.w = fmaxf((v.w - mn.w) * rq.w * gg.w + bb.w, 0.f);
        }
        *(float4*)&sr[i] = v;
    }
    __syncthreads();
    int js = (tid & 15) * 4;  // out channels
    int r  = tid >> 4;        // node group, nodes r*4 .. r*4+3
    float4 bb = *(const float4*)&b2[js];
    float acc[4][4];
#pragma unroll
    for (int i = 0; i < 4; ++i) { acc[i][0]=bb.x; acc[i][1]=bb.y; acc[i][2]=bb.z; acc[i][3]=bb.w; }
#pragma unroll 4
    for (int k = 0; k < CHID; ++k) {
        float4 w = *(float4*)&sW[k * COUT + js];
#pragma unroll
        for (int i = 0; i < 4; ++i) {
            float a = sr[(r * 4 + i) * CHID + k];
            acc[i][0] = fmaf(a, w.x, acc[i][0]);
            acc[i][1] = fmaf(a, w.y, acc[i][1]);
            acc[i][2] = fmaf(a, w.z, acc[i][2]);
            acc[i][3] = fmaf(a, w.w, acc[i][3]);
        }
    }
    float s1[4] = {0,0,0,0}, s2[4] = {0,0,0,0};
#pragma unroll
    for (int i = 0; i < 4; ++i) {
        int node = nbase + r * 4 + i;
        if (node < N_NODES) {
            *(float4*)&h2[(long)node * COUT + js] =
                make_float4(acc[i][0], acc[i][1], acc[i][2], acc[i][3]);
#pragma unroll
            for (int jj = 0; jj < 4; ++jj) {
                s1[jj] += acc[i][jj];
                s2[jj] += acc[i][jj] * acc[i][jj];
            }
        }
    }
    // in-block stat reduction: 16 r-groups -> one row of 128 (64 s1 | 64 s2)
    __syncthreads();
    float* red = sW;                 // [16][64] s1, then [16][64] s2
    *(float4*)&red[r * 64 + js]        = make_float4(s1[0], s1[1], s1[2], s1[3]);
    *(float4*)&red[1024 + r * 64 + js] = make_float4(s2[0], s2[1], s2[2], s2[3]);
    __syncthreads();
    if (tid < 128) {
        int base = (tid < 64) ? tid : (1024 + tid - 64);
        float v = 0.f;
#pragma unroll
        for (int rr = 0; rr < 16; ++rr) v += red[base + rr * 64];
        P[(long)blockIdx.x * 128 + tid] = v;
    }
}

// ---------------- GEMM3: t3 = silu(BN2(h2)) @ Wl, in-block BN3 row ----------
__global__ void __launch_bounds__(256) gemm3_kernel(
        const float* __restrict__ h2, const float* __restrict__ mr2,
        const float* __restrict__ g, const float* __restrict__ be,
        const float* __restrict__ Wl,
        float* __restrict__ t3, float* __restrict__ P) {
    __shared__ float sW[COUT * COUT]; // 16 KiB (reused as stat scratch)
    __shared__ float sr[NT * COUT];   // 16 KiB
    int tid = threadIdx.x;
    int nbase = blockIdx.x * NT;
    for (int i = tid * 4; i < COUT * COUT; i += 1024)
        *(float4*)&sW[i] = *(const float4*)&Wl[i];
    for (int i = tid * 4; i < NT * COUT; i += 1024) {
        int node = nbase + (i >> 6);
        int j = i & 63;
        float4 v = make_float4(0.f, 0.f, 0.f, 0.f);
        if (node < N_NODES) {
            v = *(const float4*)&h2[(long)node * COUT + j];
            float4 mn = *(const float4*)&mr2[j];
            float4 rq = *(const float4*)&mr2[COUT + j];
            float4 gg = *(const float4*)&g[j];
            float4 bb = *(const float4*)&be[j];
            v.x = (v.x - mn.x) * rq.x * gg.x + bb.x;
            v.y = (v.y - mn.y) * rq.y * gg.y + bb.y;
            v.z = (v.z - mn.z) * rq.z * gg.z + bb.z;
            v.w = (v.w - mn.w) * rq.w * gg.w + bb.w;
            v.x = v.x / (1.f + __expf(-v.x));
            v.y = v.y / (1.f + __expf(-v.y));
            v.z = v.z / (1.f + __expf(-v.z));
            v.w = v.w / (1.f + __expf(-v.w));
        }
        *(float4*)&sr[i] = v;
    }
    __syncthreads();
    int js = (tid & 15) * 4;
    int r  = tid >> 4;
    float acc[4][4];
#pragma unroll
    for (int i = 0; i < 4; ++i) { acc[i][0]=0.f; acc[i][1]=0.f; acc[i][2]=0.f; acc[i][3]=0.f; }
#pragma unroll 4
    for (int k = 0; k < COUT; ++k) {
        float4 w = *(float4*)&sW[k * COUT + js];
#pragma unroll
        for (int i = 0; i < 4; ++i) {
            float a = sr[(r * 4 + i) * COUT + k];
            acc[i][0] = fmaf(a, w.x, acc[i][0]);
            acc[i][1] = fmaf(a, w.y, acc[i][1]);
            acc[i][2] = fmaf(a, w.z, acc[i][2]);
            acc[i][3] = fmaf(a, w.w, acc[i][3]);
        }
    }
    float s1[4] = {0,0,0,0}, s2[4] = {0,0,0,0};
#pragma unroll
    for (int i = 0; i < 4; ++i) {
        int node = nbase + r * 4 + i;
        if (node < N_NODES) {
            *(float4*)&t3[(long)node * COUT + js] =
                make_float4(acc[i][0], acc[i][1], acc[i][2], acc[i][3]);
#pragma unroll
            for (int jj = 0; jj < 4; ++jj) {
                s1[jj] += acc[i][jj];
                s2[jj] += acc[i][jj] * acc[i][jj];
            }
        }
    }
    __syncthreads();
    float* red = sW;
    *(float4*)&red[r * 64 + js]        = make_float4(s1[0], s1[1], s1[2], s1[3]);
    *(float4*)&red[1024 + r * 64 + js] = make_float4(s2[0], s2[1], s2[2], s2[3]);
    __syncthreads();
    if (tid < 128) {
        int base = (tid < 64) ? tid : (1024 + tid - 64);
        float v = 0.f;
#pragma unroll
        for (int rr = 0; rr < 16; ++rr) v += red[base + rr * 64];
        P[(long)blockIdx.x * 128 + tid] = v;
    }
}

// ---------------- final: out = silu(BN3(t3)), float4 ------------------------
__global__ void final_kernel(const float* __restrict__ t3, const float* __restrict__ mr3,
                             const float* __restrict__ g, const float* __restrict__ be,
                             float* __restrict__ out) {
    long i = ((long)blockIdx.x * blockDim.x + threadIdx.x) * 4;
    int j = (int)(i & 63);
    float4 v = *(const float4*)&t3[i];
    float4 mn = *(const float4*)&mr3[j];
    float4 rq = *(const float4*)&mr3[COUT + j];
    float4 gg = *(const float4*)&g[j];
    float4 bb = *(const float4*)&be[j];
    v.x = (v.x - mn.x) * rq.x * gg.x + bb.x;
    v.y = (v.y - mn.y) * rq.y * gg.y + bb.y;
    v.z = (v.z - mn.z) * rq.z * gg.z + bb.z;
    v.w = (v.w - mn.w) * rq.w * gg.w + bb.w;
    v.x = v.x / (1.f + __expf(-v.x));
    v.y = v.y / (1.f + __expf(-v.y));
    v.z = v.z / (1.f + __expf(-v.z));
    v.w = v.w / (1.f + __expf(-v.w));
    *(float4*)&out[i] = v;
}

extern "C" void kernel_launch(void* const* d_in, const int* in_sizes, int n_in,
                              void* d_out, int out_size, void* d_ws, size_t ws_size,
                              hipStream_t stream) {
    const float* x   = (const float*)d_in[0];
    const int*   ei  = (const int*)d_in[1];
    const float* ea  = (const float*)d_in[2];
    const float* W1  = (const float*)d_in[4];
    const float* b1  = (const float*)d_in[5];
    const float* gm  = (const float*)d_in[6];
    const float* bm  = (const float*)d_in[7];
    const float* W2  = (const float*)d_in[8];
    const float* b2  = (const float*)d_in[9];
    const float* g1  = (const float*)d_in[10];
    const float* be1 = (const float*)d_in[11];
    const float* Wl  = (const float*)d_in[12];
    const float* g2  = (const float*)d_in[13];
    const float* be2 = (const float*)d_in[14];
    float* out = (float*)d_out;

    // workspace layout (floats):
    //   h0[N*64] | t1[N*128] | h2[N*64] | Sfin[512] | Q[16384] | cnt[N] |
    //   tickets[4] | pad | es[N*CAP int2]
    // stat partials alias dead regions: P1->h2, P2->h0, P3->t1
    float* h0   = (float*)d_ws;
    float* t1   = h0 + (long)N_NODES * CIN;
    float* h2   = t1 + (long)N_NODES * CHID;
    float* t3   = h0;
    float* Sfin = h2 + (long)N_NODES * COUT;
    float* Q    = Sfin + 512;
    int*   cnt  = (int*)(Q + RBLK * 256);
    int*   tickets = cnt + N_NODES;
    long   es_off = ((long)(N_NODES * CIN) + (long)N_NODES * CHID + (long)N_NODES * COUT
                     + 512 + RBLK * 256 + N_NODES + 4 + 255) & ~255L;
    int2*  es   = (int2*)((float*)d_ws + es_off);
    float* P1 = h2;
    float* P2 = h0;
    float* P3 = t1;

    const float invN = 1.f / N_NODES;

    hipMemsetAsync(cnt, 0, ((size_t)N_NODES + 4) * sizeof(int), stream);

    bucket_kernel<<<(E_EDGES / 4 + 255) / 256, 256, 0, stream>>>(ei, cnt, es);
    gather_kernel<<<(N_NODES * 64 + 255) / 256, 256, 0, stream>>>(x, ea, es, cnt, h0);

    // P is one row per GEMM block: totrows = NB for all three stages
    const int rpA = (NB + RBLK - 1) / RBLK;   // 25

    gemm1_kernel<<<NB, 256, 0, stream>>>(h0, W1, b1, t1, P1);
    reduce_slab_kernel<<<RBLK, 256, 0, stream>>>(P1, NB, rpA, Q, Sfin, CHID, invN, tickets + 0);
    gemm2_kernel<<<NB, 256, 0, stream>>>(t1, Sfin, gm, bm, W2, b2, h2, P2);
    reduce_slab_kernel<<<RBLK, 128, 0, stream>>>(P2, NB, rpA, Q, Sfin + 256, COUT, invN, tickets + 1);
    gemm3_kernel<<<NB, 256, 0, stream>>>(h2, Sfin + 256, g1, be1, Wl, t3, P3);
    reduce_slab_kernel<<<RBLK, 128, 0, stream>>>(P3, NB, rpA, Q, Sfin + 384, COUT, invN, tickets + 2);
    final_kernel<<<(N_NODES * COUT / 4) / 256, 256, 0, stream>>>(t3, Sfin + 384, g2, be2, out);
}

// Round 14
// 384.280 us; speedup vs baseline: 1.1703x; 1.0182x over previous
//
#include <hip/hip_runtime.h>

#define N_NODES 100000
#define E_EDGES 1600000
#define CIN 64
#define CHID 128
#define COUT 64
#define NT 64                         // nodes per GEMM block
#define NB ((N_NODES + NT - 1) / NT)  // 1563
#define RBLK 64                       // slab blocks for stat reduce
#define CAP 128                       // bucket capacity per node

// ---------------- bucket scatter: counting-sort-free CSR, 4 edges/thread ----
__global__ void bucket_kernel(const int* __restrict__ ei, int* __restrict__ cnt,
                              int2* __restrict__ es) {
    int e4 = (blockIdx.x * blockDim.x + threadIdx.x) * 4;
    if (e4 >= E_EDGES) return;
    int4 s = *(const int4*)&ei[e4];
    int4 d = *(const int4*)&ei[E_EDGES + e4];
    int p0 = atomicAdd(&cnt[d.x], 1);
    if (p0 < CAP) es[((long)d.x << 7) + p0] = make_int2(e4 + 0, s.x);
    int p1 = atomicAdd(&cnt[d.y], 1);
    if (p1 < CAP) es[((long)d.y << 7) + p1] = make_int2(e4 + 1, s.y);
    int p2 = atomicAdd(&cnt[d.z], 1);
    if (p2 < CAP) es[((long)d.z << 7) + p2] = make_int2(e4 + 2, s.z);
    int p3 = atomicAdd(&cnt[d.w], 1);
    if (p3 < CAP) es[((long)d.w << 7) + p3] = make_int2(e4 + 3, s.w);
}

// ---------------- gather: softmax-aggregate per node, fuse root add --------
// R11 proven form: lane = channel, 16-deep main loop, nontemporal ea.
__global__ void gather_kernel(const float* __restrict__ x,
                              const float* __restrict__ ea,
                              const int2* __restrict__ es,
                              const int* __restrict__ cnt,
                              float* __restrict__ h0) {
    int node = (blockIdx.x * blockDim.x + threadIdx.x) >> 6;
    int lane = threadIdx.x & 63;
    if (node >= N_NODES) return;
    long s = (long)node << 7;
    int n = cnt[node];
    n = n > CAP ? CAP : n;
    float nm = 0.f, dn = 0.f;
    int p = 0;
    for (; p + 16 <= n; p += 16) {
        int2 q[16];
#pragma unroll
        for (int u = 0; u < 16; ++u) q[u] = es[s + p + u];
        float av[16], xv[16];
#pragma unroll
        for (int u = 0; u < 16; ++u)
            av[u] = __builtin_nontemporal_load(ea + (long)q[u].x * CIN + lane);
#pragma unroll
        for (int u = 0; u < 16; ++u) xv[u] = x[(long)q[u].y * CIN + lane];
#pragma unroll
        for (int u = 0; u < 16; ++u) {
            float m = fmaxf(xv[u] + av[u], 0.f) + 1e-7f;
            float ex = __expf(m);
            nm = fmaf(m, ex, nm);
            dn += ex;
        }
    }
    for (; p + 8 <= n; p += 8) {
        int2 q[8];
#pragma unroll
        for (int u = 0; u < 8; ++u) q[u] = es[s + p + u];
        float av[8], xv[8];
#pragma unroll
        for (int u = 0; u < 8; ++u)
            av[u] = __builtin_nontemporal_load(ea + (long)q[u].x * CIN + lane);
#pragma unroll
        for (int u = 0; u < 8; ++u) xv[u] = x[(long)q[u].y * CIN + lane];
#pragma unroll
        for (int u = 0; u < 8; ++u) {
            float m = fmaxf(xv[u] + av[u], 0.f) + 1e-7f;
            float ex = __expf(m);
            nm = fmaf(m, ex, nm);
            dn += ex;
        }
    }
    for (; p + 4 <= n; p += 4) {
        int2 q[4];
#pragma unroll
        for (int u = 0; u < 4; ++u) q[u] = es[s + p + u];
        float av[4], xv[4];
#pragma unroll
        for (int u = 0; u < 4; ++u)
            av[u] = __builtin_nontemporal_load(ea + (long)q[u].x * CIN + lane);
#pragma unroll
        for (int u = 0; u < 4; ++u) xv[u] = x[(long)q[u].y * CIN + lane];
#pragma unroll
        for (int u = 0; u < 4; ++u) {
            float m = fmaxf(xv[u] + av[u], 0.f) + 1e-7f;
            float ex = __expf(m);
            nm = fmaf(m, ex, nm);
            dn += ex;
        }
    }
    for (; p < n; ++p) {
        int2 q = es[s + p];
        float m = fmaxf(x[(long)q.y * CIN + lane] + ea[(long)q.x * CIN + lane], 0.f) + 1e-7f;
        float ex = __expf(m);
        nm = fmaf(m, ex, nm);
        dn += ex;
    }
    h0[(long)node * CIN + lane] = nm / (dn + 1e-16f) + x[(long)node * CIN + lane];
}

// ---------------- slab reduce with last-block-fused finalize ----------------
// P is ONE row per GEMM block (in-block pre-reduced).
__global__ void reduce_slab_kernel(const float* __restrict__ P, int totrows,
                                   int rows_per, float* __restrict__ Q,
                                   float* __restrict__ mr, int C, float invN,
                                   int* __restrict__ ticket) {
    int C2 = blockDim.x;
    int t = threadIdx.x;
    long r0 = (long)blockIdx.x * rows_per;
    long r1 = r0 + rows_per;
    if (r1 > totrows) r1 = totrows;
    {
        float s0 = 0.f, s1 = 0.f, s2 = 0.f, s3 = 0.f;
        long r = r0;
        for (; r + 4 <= r1; r += 4) {
            s0 += P[(r + 0) * C2 + t];
            s1 += P[(r + 1) * C2 + t];
            s2 += P[(r + 2) * C2 + t];
            s3 += P[(r + 3) * C2 + t];
        }
        for (; r < r1; ++r) s0 += P[r * C2 + t];
        Q[(long)blockIdx.x * C2 + t] = (s0 + s1) + (s2 + s3);
    }
    __threadfence();
    __shared__ int lastFlag;
    if (t == 0) lastFlag = (atomicAdd(ticket, 1) == (int)gridDim.x - 1);
    __syncthreads();
    if (!lastFlag) return;
    __threadfence();
    float s0 = 0.f, s1 = 0.f, s2 = 0.f, s3 = 0.f;
    for (int r = 0; r < RBLK; r += 4) {
        s0 += Q[(long)(r + 0) * C2 + t];
        s1 += Q[(long)(r + 1) * C2 + t];
        s2 += Q[(long)(r + 2) * C2 + t];
        s3 += Q[(long)(r + 3) * C2 + t];
    }
    __shared__ float sm[256];
    sm[t] = (s0 + s1) + (s2 + s3);
    __syncthreads();
    if (t < C) {
        float m = sm[t] * invN;
        float v = sm[C + t] * invN - m * m;
        mr[t] = m;
        mr[C + t] = rsqrtf(fmaxf(v, 0.f) + 1e-5f);
    }
}

// ---------------- GEMM1: t1 = h0 @ W1 + b1, in-block BN1 partial row --------
__global__ void __launch_bounds__(256) gemm1_kernel(
        const float* __restrict__ h0, const float* __restrict__ W1,
        const float* __restrict__ b1, float* __restrict__ t1,
        float* __restrict__ P) {
    __shared__ float sW[CIN * CHID];  // 32 KiB (reused as stat scratch)
    __shared__ float sh[NT * CIN];    // 16 KiB
    int tid = threadIdx.x;
    int nbase = blockIdx.x * NT;
    for (int i = tid * 4; i < CIN * CHID; i += 1024)
        *(float4*)&sW[i] = *(const float4*)&W1[i];
    for (int i = tid * 4; i < NT * CIN; i += 1024) {
        int node = nbase + (i >> 6);
        float4 v = make_float4(0.f, 0.f, 0.f, 0.f);
        if (node < N_NODES) v = *(const float4*)&h0[(long)node * CIN + (i & 63)];
        *(float4*)&sh[i] = v;
    }
    __syncthreads();
    int js = (tid & 31) * 4;  // out channels js..js+3
    int r  = tid >> 5;        // node group, nodes r*8 .. r*8+7
    float4 bb = *(const float4*)&b1[js];
    float acc[8][4];
#pragma unroll
    for (int i = 0; i < 8; ++i) { acc[i][0]=bb.x; acc[i][1]=bb.y; acc[i][2]=bb.z; acc[i][3]=bb.w; }
#pragma unroll 4
    for (int k = 0; k < CIN; ++k) {
        float4 w = *(float4*)&sW[k * CHID + js];
#pragma unroll
        for (int i = 0; i < 8; ++i) {
            float a = sh[(r * 8 + i) * CIN + k];
            acc[i][0] = fmaf(a, w.x, acc[i][0]);
            acc[i][1] = fmaf(a, w.y, acc[i][1]);
            acc[i][2] = fmaf(a, w.z, acc[i][2]);
            acc[i][3] = fmaf(a, w.w, acc[i][3]);
        }
    }
    float s1[4] = {0,0,0,0}, s2[4] = {0,0,0,0};
#pragma unroll
    for (int i = 0; i < 8; ++i) {
        int node = nbase + r * 8 + i;
        if (node < N_NODES) {
            *(float4*)&t1[(long)node * CHID + js] =
                make_float4(acc[i][0], acc[i][1], acc[i][2], acc[i][3]);
#pragma unroll
            for (int jj = 0; jj < 4; ++jj) {
                s1[jj] += acc[i][jj];
                s2[jj] += acc[i][jj] * acc[i][jj];
            }
        }
    }
    // in-block stat reduction: 8 r-groups -> one row of 256 (128 s1 | 128 s2)
    __syncthreads();                 // all sW reads done; safe to reuse
    float* red = sW;                 // [8][128] s1, then [8][128] s2
    *(float4*)&red[r * 128 + js]        = make_float4(s1[0], s1[1], s1[2], s1[3]);
    *(float4*)&red[1024 + r * 128 + js] = make_float4(s2[0], s2[1], s2[2], s2[3]);
    __syncthreads();
    {
        int base = (tid < 128) ? tid : (1024 + tid - 128);
        float v = 0.f;
#pragma unroll
        for (int rr = 0; rr < 8; ++rr) v += red[base + rr * 128];
        P[(long)blockIdx.x * 256 + tid] = v;
    }
}

// ---------------- GEMM2: h2 = relu(BN1(t1)) @ W2 + b2, in-block BN2 row -----
__global__ void __launch_bounds__(256) gemm2_kernel(
        const float* __restrict__ t1, const float* __restrict__ mr1,
        const float* __restrict__ g, const float* __restrict__ be,
        const float* __restrict__ W2, const float* __restrict__ b2,
        float* __restrict__ h2, float* __restrict__ P) {
    __shared__ float sW[CHID * COUT]; // 32 KiB (reused as stat scratch)
    __shared__ float sr[NT * CHID];   // 32 KiB
    int tid = threadIdx.x;
    int nbase = blockIdx.x * NT;
    for (int i = tid * 4; i < CHID * COUT; i += 1024)
        *(float4*)&sW[i] = *(const float4*)&W2[i];
    for (int i = tid * 4; i < NT * CHID; i += 1024) {
        int node = nbase + (i >> 7);
        int j = i & 127;
        float4 v = make_float4(0.f, 0.f, 0.f, 0.f);
        if (node < N_NODES) {
            v = *(const float4*)&t1[(long)node * CHID + j];
            float4 mn = *(const float4*)&mr1[j];
            float4 rq = *(const float4*)&mr1[CHID + j];
            float4 gg = *(const float4*)&g[j];
            float4 bb = *(const float4*)&be[j];
            v.x = fmaxf((v.x - mn.x) * rq.x * gg.x + bb.x, 0.f);
            v.y = fmaxf((v.y - mn.y) * rq.y * gg.y + bb.y, 0.f);
            v.z = fmaxf((v.z - mn.z) * rq.z * gg.z + bb.z, 0.f);
            v.w = fmaxf((v.w - mn.w) * rq.w * gg.w + bb.w, 0.f);
        }
        *(float4*)&sr[i] = v;
    }
    __syncthreads();
    int js = (tid & 15) * 4;  // out channels
    int r  = tid >> 4;        // node group, nodes r*4 .. r*4+3
    float4 bb = *(const float4*)&b2[js];
    float acc[4][4];
#pragma unroll
    for (int i = 0; i < 4; ++i) { acc[i][0]=bb.x; acc[i][1]=bb.y; acc[i][2]=bb.z; acc[i][3]=bb.w; }
#pragma unroll 4
    for (int k = 0; k < CHID; ++k) {
        float4 w = *(float4*)&sW[k * COUT + js];
#pragma unroll
        for (int i = 0; i < 4; ++i) {
            float a = sr[(r * 4 + i) * CHID + k];
            acc[i][0] = fmaf(a, w.x, acc[i][0]);
            acc[i][1] = fmaf(a, w.y, acc[i][1]);
            acc[i][2] = fmaf(a, w.z, acc[i][2]);
            acc[i][3] = fmaf(a, w.w, acc[i][3]);
        }
    }
    float s1[4] = {0,0,0,0}, s2[4] = {0,0,0,0};
#pragma unroll
    for (int i = 0; i < 4; ++i) {
        int node = nbase + r * 4 + i;
        if (node < N_NODES) {
            *(float4*)&h2[(long)node * COUT + js] =
                make_float4(acc[i][0], acc[i][1], acc[i][2], acc[i][3]);
#pragma unroll
            for (int jj = 0; jj < 4; ++jj) {
                s1[jj] += acc[i][jj];
                s2[jj] += acc[i][jj] * acc[i][jj];
            }
        }
    }
    // in-block stat reduction: 16 r-groups -> one row of 128 (64 s1 | 64 s2)
    __syncthreads();
    float* red = sW;                 // [16][64] s1, then [16][64] s2
    *(float4*)&red[r * 64 + js]        = make_float4(s1[0], s1[1], s1[2], s1[3]);
    *(float4*)&red[1024 + r * 64 + js] = make_float4(s2[0], s2[1], s2[2], s2[3]);
    __syncthreads();
    if (tid < 128) {
        int base = (tid < 64) ? tid : (1024 + tid - 64);
        float v = 0.f;
#pragma unroll
        for (int rr = 0; rr < 16; ++rr) v += red[base + rr * 64];
        P[(long)blockIdx.x * 128 + tid] = v;
    }
}

// ---------------- GEMM3: t3 = silu(BN2(h2)) @ Wl, in-block BN3 row ----------
__global__ void __launch_bounds__(256) gemm3_kernel(
        const float* __restrict__ h2, const float* __restrict__ mr2,
        const float* __restrict__ g, const float* __restrict__ be,
        const float* __restrict__ Wl,
        float* __restrict__ t3, float* __restrict__ P) {
    __shared__ float sW[COUT * COUT]; // 16 KiB (reused as stat scratch)
    __shared__ float sr[NT * COUT];   // 16 KiB
    int tid = threadIdx.x;
    int nbase = blockIdx.x * NT;
    for (int i = tid * 4; i < COUT * COUT; i += 1024)
        *(float4*)&sW[i] = *(const float4*)&Wl[i];
    for (int i = tid * 4; i < NT * COUT; i += 1024) {
        int node = nbase + (i >> 6);
        int j = i & 63;
        float4 v = make_float4(0.f, 0.f, 0.f, 0.f);
        if (node < N_NODES) {
            v = *(const float4*)&h2[(long)node * COUT + j];
            float4 mn = *(const float4*)&mr2[j];
            float4 rq = *(const float4*)&mr2[COUT + j];
            float4 gg = *(const float4*)&g[j];
            float4 bb = *(const float4*)&be[j];
            v.x = (v.x - mn.x) * rq.x * gg.x + bb.x;
            v.y = (v.y - mn.y) * rq.y * gg.y + bb.y;
            v.z = (v.z - mn.z) * rq.z * gg.z + bb.z;
            v.w = (v.w - mn.w) * rq.w * gg.w + bb.w;
            v.x = v.x / (1.f + __expf(-v.x));
            v.y = v.y / (1.f + __expf(-v.y));
            v.z = v.z / (1.f + __expf(-v.z));
            v.w = v.w / (1.f + __expf(-v.w));
        }
        *(float4*)&sr[i] = v;
    }
    __syncthreads();
    int js = (tid & 15) * 4;
    int r  = tid >> 4;
    float acc[4][4];
#pragma unroll
    for (int i = 0; i < 4; ++i) { acc[i][0]=0.f; acc[i][1]=0.f; acc[i][2]=0.f; acc[i][3]=0.f; }
#pragma unroll 4
    for (int k = 0; k < COUT; ++k) {
        float4 w = *(float4*)&sW[k * COUT + js];
#pragma unroll
        for (int i = 0; i < 4; ++i) {
            float a = sr[(r * 4 + i) * COUT + k];
            acc[i][0] = fmaf(a, w.x, acc[i][0]);
            acc[i][1] = fmaf(a, w.y, acc[i][1]);
            acc[i][2] = fmaf(a, w.z, acc[i][2]);
            acc[i][3] = fmaf(a, w.w, acc[i][3]);
        }
    }
    float s1[4] = {0,0,0,0}, s2[4] = {0,0,0,0};
#pragma unroll
    for (int i = 0; i < 4; ++i) {
        int node = nbase + r * 4 + i;
        if (node < N_NODES) {
            *(float4*)&t3[(long)node * COUT + js] =
                make_float4(acc[i][0], acc[i][1], acc[i][2], acc[i][3]);
#pragma unroll
            for (int jj = 0; jj < 4; ++jj) {
                s1[jj] += acc[i][jj];
                s2[jj] += acc[i][jj] * acc[i][jj];
            }
        }
    }
    __syncthreads();
    float* red = sW;
    *(float4*)&red[r * 64 + js]        = make_float4(s1[0], s1[1], s1[2], s1[3]);
    *(float4*)&red[1024 + r * 64 + js] = make_float4(s2[0], s2[1], s2[2], s2[3]);
    __syncthreads();
    if (tid < 128) {
        int base = (tid < 64) ? tid : (1024 + tid - 64);
        float v = 0.f;
#pragma unroll
        for (int rr = 0; rr < 16; ++rr) v += red[base + rr * 64];
        P[(long)blockIdx.x * 128 + tid] = v;
    }
}

// ---------------- final: out = silu(BN3(t3)), float4 ------------------------
__global__ void final_kernel(const float* __restrict__ t3, const float* __restrict__ mr3,
                             const float* __restrict__ g, const float* __restrict__ be,
                             float* __restrict__ out) {
    long i = ((long)blockIdx.x * blockDim.x + threadIdx.x) * 4;
    int j = (int)(i & 63);
    float4 v = *(const float4*)&t3[i];
    float4 mn = *(const float4*)&mr3[j];
    float4 rq = *(const float4*)&mr3[COUT + j];
    float4 gg = *(const float4*)&g[j];
    float4 bb = *(const float4*)&be[j];
    v.x = (v.x - mn.x) * rq.x * gg.x + bb.x;
    v.y = (v.y - mn.y) * rq.y * gg.y + bb.y;
    v.z = (v.z - mn.z) * rq.z * gg.z + bb.z;
    v.w = (v.w - mn.w) * rq.w * gg.w + bb.w;
    v.x = v.x / (1.f + __expf(-v.x));
    v.y = v.y / (1.f + __expf(-v.y));
    v.z = v.z / (1.f + __expf(-v.z));
    v.w = v.w / (1.f + __expf(-v.w));
    *(float4*)&out[i] = v;
}

extern "C" void kernel_launch(void* const* d_in, const int* in_sizes, int n_in,
                              void* d_out, int out_size, void* d_ws, size_t ws_size,
                              hipStream_t stream) {
    const float* x   = (const float*)d_in[0];
    const int*   ei  = (const int*)d_in[1];
    const float* ea  = (const float*)d_in[2];
    const float* W1  = (const float*)d_in[4];
    const float* b1  = (const float*)d_in[5];
    const float* gm  = (const float*)d_in[6];
    const float* bm  = (const float*)d_in[7];
    const float* W2  = (const float*)d_in[8];
    const float* b2  = (const float*)d_in[9];
    const float* g1  = (const float*)d_in[10];
    const float* be1 = (const float*)d_in[11];
    const float* Wl  = (const float*)d_in[12];
    const float* g2  = (const float*)d_in[13];
    const float* be2 = (const float*)d_in[14];
    float* out = (float*)d_out;

    // workspace layout (floats):
    //   h0[N*64] | t1[N*128] | h2[N*64] | Sfin[512] | Q[16384] | cnt[N] |
    //   tickets[4] | pad | es[N*CAP int2]
    // stat partials alias dead regions: P1->h2, P2->h0, P3->t1
    float* h0   = (float*)d_ws;
    float* t1   = h0 + (long)N_NODES * CIN;
    float* h2   = t1 + (long)N_NODES * CHID;
    float* t3   = h0;
    float* Sfin = h2 + (long)N_NODES * COUT;
    float* Q    = Sfin + 512;
    int*   cnt  = (int*)(Q + RBLK * 256);
    int*   tickets = cnt + N_NODES;
    long   es_off = ((long)(N_NODES * CIN) + (long)N_NODES * CHID + (long)N_NODES * COUT
                     + 512 + RBLK * 256 + N_NODES + 4 + 255) & ~255L;
    int2*  es   = (int2*)((float*)d_ws + es_off);
    float* P1 = h2;
    float* P2 = h0;
    float* P3 = t1;

    const float invN = 1.f / N_NODES;

    hipMemsetAsync(cnt, 0, ((size_t)N_NODES + 4) * sizeof(int), stream);

    bucket_kernel<<<(E_EDGES / 4 + 255) / 256, 256, 0, stream>>>(ei, cnt, es);
    gather_kernel<<<(N_NODES * 64 + 255) / 256, 256, 0, stream>>>(x, ea, es, cnt, h0);

    // P is one row per GEMM block: totrows = NB for all three stages
    const int rpA = (NB + RBLK - 1) / RBLK;   // 25

    gemm1_kernel<<<NB, 256, 0, stream>>>(h0, W1, b1, t1, P1);
    reduce_slab_kernel<<<RBLK, 256, 0, stream>>>(P1, NB, rpA, Q, Sfin, CHID, invN, tickets + 0);
    gemm2_kernel<<<NB, 256, 0, stream>>>(t1, Sfin, gm, bm, W2, b2, h2, P2);
    reduce_slab_kernel<<<RBLK, 128, 0, stream>>>(P2, NB, rpA, Q, Sfin + 256, COUT, invN, tickets + 1);
    gemm3_kernel<<<NB, 256, 0, stream>>>(h2, Sfin + 256, g1, be1, Wl, t3, P3);
    reduce_slab_kernel<<<RBLK, 128, 0, stream>>>(P3, NB, rpA, Q, Sfin + 384, COUT, invN, tickets + 2);
    final_kernel<<<(N_NODES * COUT / 4) / 256, 256, 0, stream>>>(t3, Sfin + 384, g2, be2, out);
}

// Round 15
// 374.621 us; speedup vs baseline: 1.2005x; 1.0258x over previous
//
#include <hip/hip_runtime.h>

#define N_NODES 100000
#define E_EDGES 1600000
#define CIN 64
#define CHID 128
#define COUT 64
#define NT 64                         // nodes per GEMM block
#define NB ((N_NODES + NT - 1) / NT)  // 1563
#define RBLK 64                       // slab blocks for stat reduce
#define CAP 128                       // bucket capacity per node

// ---------------- bucket scatter: counting-sort-free CSR --------------------
// 1 edge/thread (R11-proven; int4 4-edge variant measured +15.6us — rejected)
__global__ void bucket_kernel(const int* __restrict__ ei, int* __restrict__ cnt,
                              int2* __restrict__ es) {
    int e = blockIdx.x * blockDim.x + threadIdx.x;
    if (e < E_EDGES) {
        int src = ei[e];
        int dst = ei[E_EDGES + e];
        int p = atomicAdd(&cnt[dst], 1);
        if (p < CAP) es[((long)dst << 7) + p] = make_int2(e, src);
    }
}

// ---------------- gather: softmax-aggregate per node, fuse root add --------
// aggr = sum(msg*exp(msg)) / (sum(exp(msg)) + 1e-16); exp(max) cancels vs ref.
// R11-proven: lane = channel, 16-deep main loop (32 rows in flight),
// nontemporal ea (streamed once; preserve L2 for x).
__global__ void gather_kernel(const float* __restrict__ x,
                              const float* __restrict__ ea,
                              const int2* __restrict__ es,
                              const int* __restrict__ cnt,
                              float* __restrict__ h0) {
    int node = (blockIdx.x * blockDim.x + threadIdx.x) >> 6;
    int lane = threadIdx.x & 63;
    if (node >= N_NODES) return;
    long s = (long)node << 7;
    int n = cnt[node];
    n = n > CAP ? CAP : n;
    float nm = 0.f, dn = 0.f;
    int p = 0;
    for (; p + 16 <= n; p += 16) {
        int2 q[16];
#pragma unroll
        for (int u = 0; u < 16; ++u) q[u] = es[s + p + u];
        float av[16], xv[16];
#pragma unroll
        for (int u = 0; u < 16; ++u)
            av[u] = __builtin_nontemporal_load(ea + (long)q[u].x * CIN + lane);
#pragma unroll
        for (int u = 0; u < 16; ++u) xv[u] = x[(long)q[u].y * CIN + lane];
#pragma unroll
        for (int u = 0; u < 16; ++u) {
            float m = fmaxf(xv[u] + av[u], 0.f) + 1e-7f;
            float ex = __expf(m);
            nm = fmaf(m, ex, nm);
            dn += ex;
        }
    }
    for (; p + 8 <= n; p += 8) {
        int2 q[8];
#pragma unroll
        for (int u = 0; u < 8; ++u) q[u] = es[s + p + u];
        float av[8], xv[8];
#pragma unroll
        for (int u = 0; u < 8; ++u)
            av[u] = __builtin_nontemporal_load(ea + (long)q[u].x * CIN + lane);
#pragma unroll
        for (int u = 0; u < 8; ++u) xv[u] = x[(long)q[u].y * CIN + lane];
#pragma unroll
        for (int u = 0; u < 8; ++u) {
            float m = fmaxf(xv[u] + av[u], 0.f) + 1e-7f;
            float ex = __expf(m);
            nm = fmaf(m, ex, nm);
            dn += ex;
        }
    }
    for (; p + 4 <= n; p += 4) {
        int2 q[4];
#pragma unroll
        for (int u = 0; u < 4; ++u) q[u] = es[s + p + u];
        float av[4], xv[4];
#pragma unroll
        for (int u = 0; u < 4; ++u)
            av[u] = __builtin_nontemporal_load(ea + (long)q[u].x * CIN + lane);
#pragma unroll
        for (int u = 0; u < 4; ++u) xv[u] = x[(long)q[u].y * CIN + lane];
#pragma unroll
        for (int u = 0; u < 4; ++u) {
            float m = fmaxf(xv[u] + av[u], 0.f) + 1e-7f;
            float ex = __expf(m);
            nm = fmaf(m, ex, nm);
            dn += ex;
        }
    }
    for (; p < n; ++p) {
        int2 q = es[s + p];
        float m = fmaxf(x[(long)q.y * CIN + lane] + ea[(long)q.x * CIN + lane], 0.f) + 1e-7f;
        float ex = __expf(m);
        nm = fmaf(m, ex, nm);
        dn += ex;
    }
    h0[(long)node * CIN + lane] = nm / (dn + 1e-16f) + x[(long)node * CIN + lane];
}

// ---------------- slab reduce with last-block-fused finalize ----------------
// P is ONE row per GEMM block (in-block pre-reduced).
__global__ void reduce_slab_kernel(const float* __restrict__ P, int totrows,
                                   int rows_per, float* __restrict__ Q,
                                   float* __restrict__ mr, int C, float invN,
                                   int* __restrict__ ticket) {
    int C2 = blockDim.x;
    int t = threadIdx.x;
    long r0 = (long)blockIdx.x * rows_per;
    long r1 = r0 + rows_per;
    if (r1 > totrows) r1 = totrows;
    {
        float s0 = 0.f, s1 = 0.f, s2 = 0.f, s3 = 0.f;
        long r = r0;
        for (; r + 4 <= r1; r += 4) {
            s0 += P[(r + 0) * C2 + t];
            s1 += P[(r + 1) * C2 + t];
            s2 += P[(r + 2) * C2 + t];
            s3 += P[(r + 3) * C2 + t];
        }
        for (; r < r1; ++r) s0 += P[r * C2 + t];
        Q[(long)blockIdx.x * C2 + t] = (s0 + s1) + (s2 + s3);
    }
    __threadfence();
    __shared__ int lastFlag;
    if (t == 0) lastFlag = (atomicAdd(ticket, 1) == (int)gridDim.x - 1);
    __syncthreads();
    if (!lastFlag) return;
    __threadfence();
    float s0 = 0.f, s1 = 0.f, s2 = 0.f, s3 = 0.f;
    for (int r = 0; r < RBLK; r += 4) {
        s0 += Q[(long)(r + 0) * C2 + t];
        s1 += Q[(long)(r + 1) * C2 + t];
        s2 += Q[(long)(r + 2) * C2 + t];
        s3 += Q[(long)(r + 3) * C2 + t];
    }
    __shared__ float sm[256];
    sm[t] = (s0 + s1) + (s2 + s3);
    __syncthreads();
    if (t < C) {
        float m = sm[t] * invN;
        float v = sm[C + t] * invN - m * m;
        mr[t] = m;
        mr[C + t] = rsqrtf(fmaxf(v, 0.f) + 1e-5f);
    }
}

// ---------------- GEMM1: t1 = h0 @ W1 + b1, in-block BN1 partial row --------
__global__ void __launch_bounds__(256) gemm1_kernel(
        const float* __restrict__ h0, const float* __restrict__ W1,
        const float* __restrict__ b1, float* __restrict__ t1,
        float* __restrict__ P) {
    __shared__ float sW[CIN * CHID];  // 32 KiB (reused as stat scratch)
    __shared__ float sh[NT * CIN];    // 16 KiB
    int tid = threadIdx.x;
    int nbase = blockIdx.x * NT;
    for (int i = tid * 4; i < CIN * CHID; i += 1024)
        *(float4*)&sW[i] = *(const float4*)&W1[i];
    for (int i = tid * 4; i < NT * CIN; i += 1024) {
        int node = nbase + (i >> 6);
        float4 v = make_float4(0.f, 0.f, 0.f, 0.f);
        if (node < N_NODES) v = *(const float4*)&h0[(long)node * CIN + (i & 63)];
        *(float4*)&sh[i] = v;
    }
    __syncthreads();
    int js = (tid & 31) * 4;  // out channels js..js+3
    int r  = tid >> 5;        // node group, nodes r*8 .. r*8+7
    float4 bb = *(const float4*)&b1[js];
    float acc[8][4];
#pragma unroll
    for (int i = 0; i < 8; ++i) { acc[i][0]=bb.x; acc[i][1]=bb.y; acc[i][2]=bb.z; acc[i][3]=bb.w; }
#pragma unroll 4
    for (int k = 0; k < CIN; ++k) {
        float4 w = *(float4*)&sW[k * CHID + js];
#pragma unroll
        for (int i = 0; i < 8; ++i) {
            float a = sh[(r * 8 + i) * CIN + k];
            acc[i][0] = fmaf(a, w.x, acc[i][0]);
            acc[i][1] = fmaf(a, w.y, acc[i][1]);
            acc[i][2] = fmaf(a, w.z, acc[i][2]);
            acc[i][3] = fmaf(a, w.w, acc[i][3]);
        }
    }
    float s1[4] = {0,0,0,0}, s2[4] = {0,0,0,0};
#pragma unroll
    for (int i = 0; i < 8; ++i) {
        int node = nbase + r * 8 + i;
        if (node < N_NODES) {
            *(float4*)&t1[(long)node * CHID + js] =
                make_float4(acc[i][0], acc[i][1], acc[i][2], acc[i][3]);
#pragma unroll
            for (int jj = 0; jj < 4; ++jj) {
                s1[jj] += acc[i][jj];
                s2[jj] += acc[i][jj] * acc[i][jj];
            }
        }
    }
    // in-block stat reduction: 8 r-groups -> one row of 256 (128 s1 | 128 s2)
    __syncthreads();                 // all sW reads done; safe to reuse
    float* red = sW;                 // [8][128] s1, then [8][128] s2
    *(float4*)&red[r * 128 + js]        = make_float4(s1[0], s1[1], s1[2], s1[3]);
    *(float4*)&red[1024 + r * 128 + js] = make_float4(s2[0], s2[1], s2[2], s2[3]);
    __syncthreads();
    {
        int base = (tid < 128) ? tid : (1024 + tid - 128);
        float v = 0.f;
#pragma unroll
        for (int rr = 0; rr < 8; ++rr) v += red[base + rr * 128];
        P[(long)blockIdx.x * 256 + tid] = v;
    }
}

// ---------------- GEMM2: h2 = relu(BN1(t1)) @ W2 + b2, in-block BN2 row -----
__global__ void __launch_bounds__(256) gemm2_kernel(
        const float* __restrict__ t1, const float* __restrict__ mr1,
        const float* __restrict__ g, const float* __restrict__ be,
        const float* __restrict__ W2, const float* __restrict__ b2,
        float* __restrict__ h2, float* __restrict__ P) {
    __shared__ float sW[CHID * COUT]; // 32 KiB (reused as stat scratch)
    __shared__ float sr[NT * CHID];   // 32 KiB
    int tid = threadIdx.x;
    int nbase = blockIdx.x * NT;
    for (int i = tid * 4; i < CHID * COUT; i += 1024)
        *(float4*)&sW[i] = *(const float4*)&W2[i];
    for (int i = tid * 4; i < NT * CHID; i += 1024) {
        int node = nbase + (i >> 7);
        int j = i & 127;
        float4 v = make_float4(0.f, 0.f, 0.f, 0.f);
        if (node < N_NODES) {
            v = *(const float4*)&t1[(long)node * CHID + j];
            float4 mn = *(const float4*)&mr1[j];
            float4 rq = *(const float4*)&mr1[CHID + j];
            float4 gg = *(const float4*)&g[j];
            float4 bb = *(const float4*)&be[j];
            v.x = fmaxf((v.x - mn.x) * rq.x * gg.x + bb.x, 0.f);
            v.y = fmaxf((v.y - mn.y) * rq.y * gg.y + bb.y, 0.f);
            v.z = fmaxf((v.z - mn.z) * rq.z * gg.z + bb.z, 0.f);
            v.w = fmaxf((v.w - mn.w) * rq.w * gg.w + bb.w, 0.f);
        }
        *(float4*)&sr[i] = v;
    }
    __syncthreads();
    int js = (tid & 15) * 4;  // out channels
    int r  = tid >> 4;        // node group, nodes r*4 .. r*4+3
    float4 bb = *(const float4*)&b2[js];
    float acc[4][4];
#pragma unroll
    for (int i = 0; i < 4; ++i) { acc[i][0]=bb.x; acc[i][1]=bb.y; acc[i][2]=bb.z; acc[i][3]=bb.w; }
#pragma unroll 4
    for (int k = 0; k < CHID; ++k) {
        float4 w = *(float4*)&sW[k * COUT + js];
#pragma unroll
        for (int i = 0; i < 4; ++i) {
            float a = sr[(r * 4 + i) * CHID + k];
            acc[i][0] = fmaf(a, w.x, acc[i][0]);
            acc[i][1] = fmaf(a, w.y, acc[i][1]);
            acc[i][2] = fmaf(a, w.z, acc[i][2]);
            acc[i][3] = fmaf(a, w.w, acc[i][3]);
        }
    }
    float s1[4] = {0,0,0,0}, s2[4] = {0,0,0,0};
#pragma unroll
    for (int i = 0; i < 4; ++i) {
        int node = nbase + r * 4 + i;
        if (node < N_NODES) {
            *(float4*)&h2[(long)node * COUT + js] =
                make_float4(acc[i][0], acc[i][1], acc[i][2], acc[i][3]);
#pragma unroll
            for (int jj = 0; jj < 4; ++jj) {
                s1[jj] += acc[i][jj];
                s2[jj] += acc[i][jj] * acc[i][jj];
            }
        }
    }
    // in-block stat reduction: 16 r-groups -> one row of 128 (64 s1 | 64 s2)
    __syncthreads();
    float* red = sW;                 // [16][64] s1, then [16][64] s2
    *(float4*)&red[r * 64 + js]        = make_float4(s1[0], s1[1], s1[2], s1[3]);
    *(float4*)&red[1024 + r * 64 + js] = make_float4(s2[0], s2[1], s2[2], s2[3]);
    __syncthreads();
    if (tid < 128) {
        int base = (tid < 64) ? tid : (1024 + tid - 64);
        float v = 0.f;
#pragma unroll
        for (int rr = 0; rr < 16; ++rr) v += red[base + rr * 64];
        P[(long)blockIdx.x * 128 + tid] = v;
    }
}

// ---------------- GEMM3: t3 = silu(BN2(h2)) @ Wl, in-block BN3 row ----------
__global__ void __launch_bounds__(256) gemm3_kernel(
        const float* __restrict__ h2, const float* __restrict__ mr2,
        const float* __restrict__ g, const float* __restrict__ be,
        const float* __restrict__ Wl,
        float* __restrict__ t3, float* __restrict__ P) {
    __shared__ float sW[COUT * COUT]; // 16 KiB (reused as stat scratch)
    __shared__ float sr[NT * COUT];   // 16 KiB
    int tid = threadIdx.x;
    int nbase = blockIdx.x * NT;
    for (int i = tid * 4; i < COUT * COUT; i += 1024)
        *(float4*)&sW[i] = *(const float4*)&Wl[i];
    for (int i = tid * 4; i < NT * COUT; i += 1024) {
        int node = nbase + (i >> 6);
        int j = i & 63;
        float4 v = make_float4(0.f, 0.f, 0.f, 0.f);
        if (node < N_NODES) {
            v = *(const float4*)&h2[(long)node * COUT + j];
            float4 mn = *(const float4*)&mr2[j];
            float4 rq = *(const float4*)&mr2[COUT + j];
            float4 gg = *(const float4*)&g[j];
            float4 bb = *(const float4*)&be[j];
            v.x = (v.x - mn.x) * rq.x * gg.x + bb.x;
            v.y = (v.y - mn.y) * rq.y * gg.y + bb.y;
            v.z = (v.z - mn.z) * rq.z * gg.z + bb.z;
            v.w = (v.w - mn.w) * rq.w * gg.w + bb.w;
            v.x = v.x / (1.f + __expf(-v.x));
            v.y = v.y / (1.f + __expf(-v.y));
            v.z = v.z / (1.f + __expf(-v.z));
            v.w = v.w / (1.f + __expf(-v.w));
        }
        *(float4*)&sr[i] = v;
    }
    __syncthreads();
    int js = (tid & 15) * 4;
    int r  = tid >> 4;
    float acc[4][4];
#pragma unroll
    for (int i = 0; i < 4; ++i) { acc[i][0]=0.f; acc[i][1]=0.f; acc[i][2]=0.f; acc[i][3]=0.f; }
#pragma unroll 4
    for (int k = 0; k < COUT; ++k) {
        float4 w = *(float4*)&sW[k * COUT + js];
#pragma unroll
        for (int i = 0; i < 4; ++i) {
            float a = sr[(r * 4 + i) * COUT + k];
            acc[i][0] = fmaf(a, w.x, acc[i][0]);
            acc[i][1] = fmaf(a, w.y, acc[i][1]);
            acc[i][2] = fmaf(a, w.z, acc[i][2]);
            acc[i][3] = fmaf(a, w.w, acc[i][3]);
        }
    }
    float s1[4] = {0,0,0,0}, s2[4] = {0,0,0,0};
#pragma unroll
    for (int i = 0; i < 4; ++i) {
        int node = nbase + r * 4 + i;
        if (node < N_NODES) {
            *(float4*)&t3[(long)node * COUT + js] =
                make_float4(acc[i][0], acc[i][1], acc[i][2], acc[i][3]);
#pragma unroll
            for (int jj = 0; jj < 4; ++jj) {
                s1[jj] += acc[i][jj];
                s2[jj] += acc[i][jj] * acc[i][jj];
            }
        }
    }
    __syncthreads();
    float* red = sW;
    *(float4*)&red[r * 64 + js]        = make_float4(s1[0], s1[1], s1[2], s1[3]);
    *(float4*)&red[1024 + r * 64 + js] = make_float4(s2[0], s2[1], s2[2], s2[3]);
    __syncthreads();
    if (tid < 128) {
        int base = (tid < 64) ? tid : (1024 + tid - 64);
        float v = 0.f;
#pragma unroll
        for (int rr = 0; rr < 16; ++rr) v += red[base + rr * 64];
        P[(long)blockIdx.x * 128 + tid] = v;
    }
}

// ---------------- final: out = silu(BN3(t3)), float4 ------------------------
__global__ void final_kernel(const float* __restrict__ t3, const float* __restrict__ mr3,
                             const float* __restrict__ g, const float* __restrict__ be,
                             float* __restrict__ out) {
    long i = ((long)blockIdx.x * blockDim.x + threadIdx.x) * 4;
    int j = (int)(i & 63);
    float4 v = *(const float4*)&t3[i];
    float4 mn = *(const float4*)&mr3[j];
    float4 rq = *(const float4*)&mr3[COUT + j];
    float4 gg = *(const float4*)&g[j];
    float4 bb = *(const float4*)&be[j];
    v.x = (v.x - mn.x) * rq.x * gg.x + bb.x;
    v.y = (v.y - mn.y) * rq.y * gg.y + bb.y;
    v.z = (v.z - mn.z) * rq.z * gg.z + bb.z;
    v.w = (v.w - mn.w) * rq.w * gg.w + bb.w;
    v.x = v.x / (1.f + __expf(-v.x));
    v.y = v.y / (1.f + __expf(-v.y));
    v.z = v.z / (1.f + __expf(-v.z));
    v.w = v.w / (1.f + __expf(-v.w));
    *(float4*)&out[i] = v;
}

extern "C" void kernel_launch(void* const* d_in, const int* in_sizes, int n_in,
                              void* d_out, int out_size, void* d_ws, size_t ws_size,
                              hipStream_t stream) {
    const float* x   = (const float*)d_in[0];
    const int*   ei  = (const int*)d_in[1];
    const float* ea  = (const float*)d_in[2];
    const float* W1  = (const float*)d_in[4];
    const float* b1  = (const float*)d_in[5];
    const float* gm  = (const float*)d_in[6];
    const float* bm  = (const float*)d_in[7];
    const float* W2  = (const float*)d_in[8];
    const float* b2  = (const float*)d_in[9];
    const float* g1  = (const float*)d_in[10];
    const float* be1 = (const float*)d_in[11];
    const float* Wl  = (const float*)d_in[12];
    const float* g2  = (const float*)d_in[13];
    const float* be2 = (const float*)d_in[14];
    float* out = (float*)d_out;

    // workspace layout (floats):
    //   h0[N*64] | t1[N*128] | h2[N*64] | Sfin[512] | Q[16384] | cnt[N] |
    //   tickets[4] | pad | es[N*CAP int2]
    // stat partials alias dead regions: P1->h2, P2->h0, P3->t1
    float* h0   = (float*)d_ws;
    float* t1   = h0 + (long)N_NODES * CIN;
    float* h2   = t1 + (long)N_NODES * CHID;
    float* t3   = h0;
    float* Sfin = h2 + (long)N_NODES * COUT;
    float* Q    = Sfin + 512;
    int*   cnt  = (int*)(Q + RBLK * 256);
    int*   tickets = cnt + N_NODES;
    long   es_off = ((long)(N_NODES * CIN) + (long)N_NODES * CHID + (long)N_NODES * COUT
                     + 512 + RBLK * 256 + N_NODES + 4 + 255) & ~255L;
    int2*  es   = (int2*)((float*)d_ws + es_off);
    float* P1 = h2;
    float* P2 = h0;
    float* P3 = t1;

    const float invN = 1.f / N_NODES;

    hipMemsetAsync(cnt, 0, ((size_t)N_NODES + 4) * sizeof(int), stream);

    bucket_kernel<<<(E_EDGES + 255) / 256, 256, 0, stream>>>(ei, cnt, es);
    gather_kernel<<<(N_NODES * 64 + 255) / 256, 256, 0, stream>>>(x, ea, es, cnt, h0);

    // P is one row per GEMM block: totrows = NB for all three stages
    const int rpA = (NB + RBLK - 1) / RBLK;   // 25

    gemm1_kernel<<<NB, 256, 0, stream>>>(h0, W1, b1, t1, P1);
    reduce_slab_kernel<<<RBLK, 256, 0, stream>>>(P1, NB, rpA, Q, Sfin, CHID, invN, tickets + 0);
    gemm2_kernel<<<NB, 256, 0, stream>>>(t1, Sfin, gm, bm, W2, b2, h2, P2);
    reduce_slab_kernel<<<RBLK, 128, 0, stream>>>(P2, NB, rpA, Q, Sfin + 256, COUT, invN, tickets + 1);
    gemm3_kernel<<<NB, 256, 0, stream>>>(h2, Sfin + 256, g1, be1, Wl, t3, P3);
    reduce_slab_kernel<<<RBLK, 128, 0, stream>>>(P3, NB, rpA, Q, Sfin + 384, COUT, invN, tickets + 2);
    final_kernel<<<(N_NODES * COUT / 4) / 256, 256, 0, stream>>>(t3, Sfin + 384, g2, be2, out);
}